// Round 4
// baseline (77.057 us; speedup 1.0000x reference)
//
#include <hip/hip_runtime.h>
#include <math.h>

// Chamfer distance: B=16, N=M=2048, D=3, fp32.
// Stage 1 (512 blocks, 2/CU): block = (combo, slice-pair). Each 128-thread
//   half-block scans one 64-point opposing slice (SoA in LDS, broadcast
//   ds_read_b128) for 16 src points/thread. Packed fp32 (v_pk_fma_f32) +
//   v_min3_f32 -> 2 VALU ops per pair evaluation.
// Stage 2 (256 blocks): min over 32 slices, add |x|^2, block-sum; last block
//   (ticket pattern) sums the 256 block sums -> out[0].

typedef float v2f __attribute__((ext_vector_type(2)));

#define NPTS    2048
#define NCOMBO  32           // 2 dirs x 16 batches
#define KSLICE  32
#define SLICE   64           // NPTS / KSLICE
#define SPT     16           // src points per thread (stage 1)
#define NBLK2   256          // stage-2 grid

__device__ __forceinline__ v2f pkfma(v2f a, v2f b, v2f c) {
#if __has_builtin(__builtin_elementwise_fma)
    return __builtin_elementwise_fma(a, b, c);
#else
    v2f d; d.x = fmaf(a.x, b.x, c.x); d.y = fmaf(a.y, b.y, c.y); return d;
#endif
}

__global__ __launch_bounds__(256, 2) void chamfer_partial(
    const float* __restrict__ preds,
    const float* __restrict__ tgts,
    float* __restrict__ partial,
    int* __restrict__ counter)
{
    __shared__ __align__(16) float qx[2][SLICE];
    __shared__ __align__(16) float qy[2][SLICE];
    __shared__ __align__(16) float qz[2][SLICE];
    __shared__ __align__(16) float qw[2][SLICE];

    const int bid   = blockIdx.x;        // 0..511
    const int combo = bid & (NCOMBO - 1);
    const int spair = bid >> 5;          // 0..15
    const int dir   = combo >> 4;
    const int b     = combo & 15;

    const int sb    = threadIdx.x >> 7;  // half-block 0/1 (waves 0,1 | 2,3)
    const int tt    = threadIdx.x & 127;
    const int slice = spair * 2 + sb;

    if (bid == 0 && threadIdx.x == 0) *counter = 0;

    const float* src = (dir ? tgts : preds) + (size_t)b * NPTS * 3;
    const float* opp = (dir ? preds : tgts) + (size_t)b * NPTS * 3;

    // Stage opposing slice (SoA, |y|^2 in qw)
    if (tt < SLICE) {
        const int jj = slice * SLICE + tt;
        const float y0 = opp[3 * jj + 0];
        const float y1 = opp[3 * jj + 1];
        const float y2 = opp[3 * jj + 2];
        qx[sb][tt] = y0;
        qy[sb][tt] = y1;
        qz[sb][tt] = y2;
        qw[sb][tt] = y0 * y0 + y1 * y1 + y2 * y2;
    }

    // 16 src points per thread; nn = -2*x duplicated for packed math
    v2f nn0[SPT], nn1[SPT], nn2[SPT];
    float m[SPT];
    #pragma unroll
    for (int k = 0; k < SPT; k++) {
        const int i = tt + 128 * k;
        const float a0 = -2.0f * src[3 * i + 0];
        const float a1 = -2.0f * src[3 * i + 1];
        const float a2 = -2.0f * src[3 * i + 2];
        nn0[k] = (v2f){a0, a0};
        nn1[k] = (v2f){a1, a1};
        nn2[k] = (v2f){a2, a2};
        m[k]   = INFINITY;
    }
    __syncthreads();

    #pragma unroll 2
    for (int jg = 0; jg < SLICE / 4; jg++) {
        const float4 X = *(const float4*)&qx[sb][4 * jg];
        const float4 Y = *(const float4*)&qy[sb][4 * jg];
        const float4 Z = *(const float4*)&qz[sb][4 * jg];
        const float4 W = *(const float4*)&qw[sb][4 * jg];
        const v2f Xa = {X.x, X.y}, Xb = {X.z, X.w};
        const v2f Ya = {Y.x, Y.y}, Yb = {Y.z, Y.w};
        const v2f Za = {Z.x, Z.y}, Zb = {Z.z, Z.w};
        const v2f Wa = {W.x, W.y}, Wb = {W.z, W.w};
        #pragma unroll
        for (int k = 0; k < SPT; k++) {
            const v2f sa = pkfma(nn0[k], Xa, pkfma(nn1[k], Ya, pkfma(nn2[k], Za, Wa)));
            m[k] = fminf(fminf(m[k], sa.x), sa.y);        // v_min3_f32
            const v2f sb2 = pkfma(nn0[k], Xb, pkfma(nn1[k], Yb, pkfma(nn2[k], Zb, Wb)));
            m[k] = fminf(fminf(m[k], sb2.x), sb2.y);      // v_min3_f32
        }
    }

    float* pp = partial + ((size_t)combo * KSLICE + slice) * NPTS;
    #pragma unroll
    for (int k = 0; k < SPT; k++)
        pp[tt + 128 * k] = m[k];
}

__global__ __launch_bounds__(256) void chamfer_reduce(
    const float* __restrict__ preds,
    const float* __restrict__ tgts,
    const float* __restrict__ partial,
    float* __restrict__ blocksum,
    int* __restrict__ counter,
    float* __restrict__ out)
{
    __shared__ float wsum[4];
    __shared__ bool  amLast;

    const int idx   = blockIdx.x * 256 + threadIdx.x;   // 0..65535
    const int combo = idx >> 11;                        // uniform per block
    const int i     = idx & (NPTS - 1);
    const int dir   = combo >> 4;
    const int b     = combo & 15;

    const float* src = (dir ? tgts : preds) + (size_t)b * NPTS * 3;
    const float x0 = src[3 * i + 0];
    const float x1 = src[3 * i + 1];
    const float x2 = src[3 * i + 2];
    const float xx = x0 * x0 + x1 * x1 + x2 * x2;

    const float* pp = partial + (size_t)combo * KSLICE * NPTS + i;
    float mn = pp[0];
    #pragma unroll
    for (int s = 1; s < KSLICE; s++)
        mn = fminf(mn, pp[(size_t)s * NPTS]);

    float val = xx + mn;

    #pragma unroll
    for (int off = 32; off > 0; off >>= 1)
        val += __shfl_down(val, off, 64);

    const int lane = threadIdx.x & 63;
    const int wid  = threadIdx.x >> 6;
    if (lane == 0) wsum[wid] = val;
    __syncthreads();

    if (threadIdx.x == 0) {
        const float bsum = wsum[0] + wsum[1] + wsum[2] + wsum[3];
        __hip_atomic_store(&blocksum[blockIdx.x], bsum,
                           __ATOMIC_RELAXED, __HIP_MEMORY_SCOPE_AGENT);
        __threadfence();
        amLast = (atomicAdd(counter, 1) == NBLK2 - 1);
    }
    __syncthreads();

    if (amLast) {
        __threadfence();
        float v = __hip_atomic_load(&blocksum[threadIdx.x],
                                    __ATOMIC_RELAXED, __HIP_MEMORY_SCOPE_AGENT);
        #pragma unroll
        for (int off = 32; off > 0; off >>= 1)
            v += __shfl_down(v, off, 64);
        if (lane == 0) wsum[wid] = v;
        __syncthreads();
        if (threadIdx.x == 0)
            out[0] = wsum[0] + wsum[1] + wsum[2] + wsum[3];
    }
}

extern "C" void kernel_launch(void* const* d_in, const int* in_sizes, int n_in,
                              void* d_out, int out_size, void* d_ws, size_t ws_size,
                              hipStream_t stream) {
    const float* preds = (const float*)d_in[0];
    const float* tgts  = (const float*)d_in[1];
    float* out      = (float*)d_out;
    float* partial  = (float*)d_ws;                              // 8 MB
    float* blocksum = partial + (size_t)NCOMBO * KSLICE * NPTS;  // 256 floats
    int*   counter  = (int*)(blocksum + NBLK2);

    chamfer_partial<<<NCOMBO * (KSLICE / 2), 256, 0, stream>>>(preds, tgts, partial, counter);
    chamfer_reduce<<<NBLK2, 256, 0, stream>>>(preds, tgts, partial, blocksum, counter, out);
}